// Round 8
// baseline (393.900 us; speedup 1.0000x reference)
//
#include <hip/hip_runtime.h>

typedef unsigned short ushort_t;
typedef unsigned int uint_t;

typedef __bf16 bf16x8 __attribute__((ext_vector_type(8)));
typedef float f32x4 __attribute__((ext_vector_type(4)));

union BFU { ushort_t u; __bf16 h; };

__device__ __forceinline__ float bf2f(uint_t u) {
    union { uint_t i; float f; } v; v.i = u << 16; return v.f;
}
__device__ __forceinline__ ushort_t f2bf(float f) {
    union { float f; uint_t i; } v; v.f = f;
    uint_t r = v.i + 0x7fffu + ((v.i >> 16) & 1u);
    return (ushort_t)(r >> 16);
}
// mode: 1 = bf16 storage, 0 = fp32 storage
__device__ __forceinline__ float loadF(const void* p, size_t i, int isBf16) {
    return isBf16 ? bf2f((uint_t)((const ushort_t*)p)[i]) : ((const float*)p)[i];
}

// ---------------- dtype detection ----------------
// flags[0..10]: x,W1,b1,W2,b2,W3,b3,Wres,bres,Wlin,blin  (1=bf16, 0=fp32)
// flags[11]: edge_index is int64 (1) or int32 (0)
struct DetectArgs {
    const void* t[11];
    int elems[11];
    const int* ei;
    int* flags;
};

__global__ void k_detect(DetectArgs a) {
    int t = threadIdx.x;
    if (t < 11) {
        const uint_t* w = (const uint_t*)a.t[t];
        int n = a.elems[t] / 2; if (n > 64) n = 64;
        int cnt = 0;
        for (int i = 0; i < n; ++i) {
            uint_t field = (w[i] >> 7) & 0xFFu;
            cnt += (field >= 100u && field <= 135u);
        }
        a.flags[t] = (cnt * 10 >= n * 6) ? 1 : 0;
    } else if (t == 11) {
        int nz = 0;
        for (int i = 0; i < 64; ++i) nz += (a.ei[2 * i + 1] != 0);
        a.flags[11] = (nz == 0) ? 1 : 0;
    }
}

// ---------------- preprocessing ----------------

__global__ void k_zero(int* p, int n) {
    int i = blockIdx.x * blockDim.x + threadIdx.x;
    if (i < n) p[i] = 0;
}

__global__ void k_deg(const int* __restrict__ ei, int E, int N,
                      const int* __restrict__ flags, int* __restrict__ deg) {
    int e = blockIdx.x * blockDim.x + threadIdx.x;
    if (e < E) {
        int is64 = flags[11];
        int d = is64 ? ei[2 * E + 2 * e] : ei[E + e];
        if ((unsigned)d < (unsigned)N) atomicAdd(&deg[d], 1);
    }
}

// ---- 3-phase parallel exclusive scan of deg -> row_ptr (+ dinv/nself/cnt) ----

__global__ __launch_bounds__(256) void k_bsum(const int* __restrict__ deg, int n,
                                              int* __restrict__ bsum) {
    int base = blockIdx.x * 1024;
    int local = 0;
#pragma unroll
    for (int j = 0; j < 4; ++j) {
        int idx = base + threadIdx.x + j * 256;
        if (idx < n) local += deg[idx];
    }
    __shared__ int s[4];
#pragma unroll
    for (int off = 32; off; off >>= 1) local += __shfl_down(local, off, 64);
    if ((threadIdx.x & 63) == 0) s[threadIdx.x >> 6] = local;
    __syncthreads();
    if (threadIdx.x == 0) bsum[blockIdx.x] = s[0] + s[1] + s[2] + s[3];
}

__global__ __launch_bounds__(256) void k_bscan(int* __restrict__ bsum, int nb) {
    __shared__ int s[256];
    int t = threadIdx.x;
    int v = (t < nb) ? bsum[t] : 0;
    s[t] = v;
    __syncthreads();
    for (int off = 1; off < 256; off <<= 1) {
        int u = (t >= off) ? s[t - off] : 0;
        __syncthreads();
        s[t] += u;
        __syncthreads();
    }
    if (t < nb) bsum[t] = s[t] - v;   // exclusive
}

// writes row_ptr, dinv, nself AND pre-seeds cnt = row_ptr (fill's atomic counter)
__global__ __launch_bounds__(256) void k_rowptr(const int* __restrict__ deg,
                                                const int* __restrict__ boff, int n,
                                                int* __restrict__ row_ptr,
                                                int* __restrict__ cnt,
                                                float* __restrict__ dinv,
                                                float* __restrict__ nself) {
    __shared__ int s[256];
    int t = threadIdx.x;
    int base = blockIdx.x * 1024 + t * 4;
    int v0 = (base + 0 < n) ? deg[base + 0] : 0;
    int v1 = (base + 1 < n) ? deg[base + 1] : 0;
    int v2 = (base + 2 < n) ? deg[base + 2] : 0;
    int v3 = (base + 3 < n) ? deg[base + 3] : 0;
    int tot = v0 + v1 + v2 + v3;
    s[t] = tot;
    __syncthreads();
    for (int off = 1; off < 256; off <<= 1) {
        int u = (t >= off) ? s[t - off] : 0;
        __syncthreads();
        s[t] += u;
        __syncthreads();
    }
    int run = boff[blockIdx.x] + ((t == 0) ? 0 : s[t - 1]);
    int vals[4] = {v0, v1, v2, v3};
#pragma unroll
    for (int j = 0; j < 4; ++j) {
        int idx = base + j;
        if (idx < n) {
            row_ptr[idx] = run;
            cnt[idx] = run;
            run += vals[j];
            float df = (float)vals[j] + 1.0f;
            dinv[idx] = rsqrtf(df);
            nself[idx] = 1.0f / df;
        }
    }
    if (blockIdx.x == gridDim.x - 1 && t == 255) row_ptr[n] = boff[blockIdx.x] + s[255];
}

// fill CSR: single packed 8B store per edge {col, wgt bits}; cnt pre-seeded to row_ptr
__global__ void k_fill(const int* __restrict__ ei, int E, int N,
                       const int* __restrict__ flags,
                       int* __restrict__ cnt,
                       const float* __restrict__ dinv,
                       uint2* __restrict__ colwgt) {
    int e = blockIdx.x * blockDim.x + threadIdx.x;
    if (e < E) {
        int is64 = flags[11];
        int s = is64 ? ei[2 * e] : ei[e];
        int d = is64 ? ei[2 * E + 2 * e] : ei[E + e];
        if ((unsigned)d < (unsigned)N) {
            int pos = atomicAdd(&cnt[d], 1);
            int ss = ((unsigned)s < (unsigned)N) ? s : 0;
            float w = dinv[ss] * dinv[d];
            uint2 pk;
            pk.x = (uint_t)ss;
            pk.y = __float_as_uint(w);
            colwgt[pos] = pk;
        }
    }
}

// transpose + canonicalize weights to bf16.
// Tcat[256 x 128] = [W1^T ; Wres^T] (dual-output layer-1 GEMM); T2,T3,Tlin as before.
__global__ void k_pack(const void* __restrict__ W1, const void* __restrict__ W2,
                       const void* __restrict__ W3, const void* __restrict__ Wr,
                       const void* __restrict__ Wl, const int* __restrict__ flags,
                       ushort_t* __restrict__ Tcat, ushort_t* __restrict__ T2,
                       ushort_t* __restrict__ T3, ushort_t* __restrict__ Tl) {
    int i = blockIdx.x * blockDim.x + threadIdx.x;
    const int SQ = 128 * 128;
    if (i < 4 * SQ) {
        int m = i / SQ, r = i % SQ;
        int k = r / 128, f = r % 128;
        const void* W = (m == 0) ? W1 : (m == 1) ? W2 : (m == 2) ? W3 : Wr;
        int fid = (m == 0) ? 1 : (m == 1) ? 3 : (m == 2) ? 5 : 7;
        ushort_t* T = (m == 0) ? Tcat : (m == 1) ? T2 : (m == 2) ? T3 : (Tcat + SQ);
        T[f * 128 + k] = f2bf(loadF(W, (size_t)k * 128 + f, flags[fid]));
    } else if (i < 4 * SQ + 128 * 64) {
        int r = i - 4 * SQ;
        int k = r / 64, f = r % 64;
        Tl[f * 128 + k] = f2bf(loadF(Wl, (size_t)k * 64 + f, flags[9]));
    }
}

// ---------------- generic GEMM: A[M x 128] @ W[128 x (NCT*16)] ----------------
template <int NCT>
__global__ __launch_bounds__(256) void k_gemm(const void* __restrict__ A, int aFid, int aFix,
                                              const ushort_t* __restrict__ WT,
                                              const void* __restrict__ bias, int bFid,
                                              void* __restrict__ C, int cFix,
                                              int M, const int* __restrict__ flags) {
    const int K = 128;
    const int F = NCT * 16;
    int wave = threadIdx.x >> 6;
    int lane = threadIdx.x & 63;
    int quad = lane >> 4;
    int l16 = lane & 15;
    int rowBase = blockIdx.x * 64 + wave * 16;

    int a16 = (aFid >= 0) ? flags[aFid] : aFix;
    int c16 = cFix;

    int arow = rowBase + l16;
    if (arow >= M) arow = M - 1;

    f32x4 acc[NCT];
#pragma unroll
    for (int c = 0; c < NCT; ++c) acc[c] = (f32x4){0.f, 0.f, 0.f, 0.f};

    const ushort_t* aptr16 = (const ushort_t*)A + (size_t)arow * K + quad * 8;
    const float*    aptr32 = (const float*)A + (size_t)arow * K + quad * 8;

#pragma unroll
    for (int kk = 0; kk < K; kk += 32) {
        bf16x8 a;
        if (a16) {
            a = *(const bf16x8*)(aptr16 + kk);
        } else {
            const f32x4* p = (const f32x4*)(aptr32 + kk);
            f32x4 u0 = p[0], u1 = p[1];
#pragma unroll
            for (int j = 0; j < 4; ++j) {
                BFU e0; e0.u = f2bf(u0[j]); a[j] = e0.h;
                BFU e1; e1.u = f2bf(u1[j]); a[j + 4] = e1.h;
            }
        }
#pragma unroll
        for (int c = 0; c < NCT; ++c) {
            const ushort_t* bp = WT + (size_t)(c * 16 + l16) * K + quad * 8 + kk;
            bf16x8 b = *(const bf16x8*)bp;
            acc[c] = __builtin_amdgcn_mfma_f32_16x16x32_bf16(a, b, acc[c], 0, 0, 0);
        }
    }

    int bf = (bias && bFid >= 0) ? flags[bFid] : 1;
#pragma unroll
    for (int c = 0; c < NCT; ++c) {
        int colg = c * 16 + l16;
        float bv = bias ? loadF(bias, colg, bf) : 0.0f;
#pragma unroll
        for (int r = 0; r < 4; ++r) {
            int row = rowBase + quad * 4 + r;
            if (row < M) {
                float v = acc[c][r] + bv;
                if (c16) ((ushort_t*)C)[(size_t)row * F + colg] = f2bf(v);
                else     ((float*)C)[(size_t)row * F + colg] = v;
            }
        }
    }
}

// ---------------- layer-1 dual GEMM: H = x@W1 (bf16), Xres = x@Wres + bres (fp32) ----
__global__ __launch_bounds__(256) void k_gemm_l1(const void* __restrict__ A,
                                                 const ushort_t* __restrict__ Tcat,
                                                 const void* __restrict__ bres,
                                                 ushort_t* __restrict__ Hout,
                                                 float* __restrict__ Xres,
                                                 int M, const int* __restrict__ flags) {
    const int K = 128;
    int wave = threadIdx.x >> 6;
    int lane = threadIdx.x & 63;
    int quad = lane >> 4;
    int l16 = lane & 15;
    int rowBase = blockIdx.x * 64 + wave * 16;

    int a16 = flags[0];
    int arow = rowBase + l16;
    if (arow >= M) arow = M - 1;

    f32x4 acc[16];
#pragma unroll
    for (int c = 0; c < 16; ++c) acc[c] = (f32x4){0.f, 0.f, 0.f, 0.f};

    const ushort_t* aptr16 = (const ushort_t*)A + (size_t)arow * K + quad * 8;
    const float*    aptr32 = (const float*)A + (size_t)arow * K + quad * 8;

#pragma unroll
    for (int kk = 0; kk < K; kk += 32) {
        bf16x8 a;
        if (a16) {
            a = *(const bf16x8*)(aptr16 + kk);
        } else {
            const f32x4* p = (const f32x4*)(aptr32 + kk);
            f32x4 u0 = p[0], u1 = p[1];
#pragma unroll
            for (int j = 0; j < 4; ++j) {
                BFU e0; e0.u = f2bf(u0[j]); a[j] = e0.h;
                BFU e1; e1.u = f2bf(u1[j]); a[j + 4] = e1.h;
            }
        }
#pragma unroll
        for (int c = 0; c < 16; ++c) {
            const ushort_t* bp = Tcat + (size_t)(c * 16 + l16) * K + quad * 8 + kk;
            bf16x8 b = *(const bf16x8*)bp;
            acc[c] = __builtin_amdgcn_mfma_f32_16x16x32_bf16(a, b, acc[c], 0, 0, 0);
        }
    }

    int bf = flags[8];
#pragma unroll
    for (int c = 0; c < 16; ++c) {
        int colg = c * 16 + l16;
        float bv = (c >= 8) ? loadF(bres, colg - 128, bf) : 0.0f;
#pragma unroll
        for (int r = 0; r < 4; ++r) {
            int row = rowBase + quad * 4 + r;
            if (row < M) {
                float v = acc[c][r] + bv;
                if (c < 8) Hout[(size_t)row * 128 + colg] = f2bf(v);
                else       Xres[(size_t)row * 128 + (colg - 128)] = v;
            }
        }
    }
}

// ---------------- aggregation: one wave per node, 16B/lane quad-gather ----------------
// H bf16 [n x 128]. Wave's 4 quads gather 4 different edges' rows per load instruction
// (lane loads uint4 = 8 feats). 2-deep unroll -> 8 edges / 2 loads in flight.
// Per-quad partial accs reduced via shfl_xor(16,32) at the end.
__global__ __launch_bounds__(256) void k_agg(const ushort_t* __restrict__ H,
                                             const int* __restrict__ row_ptr,
                                             const uint2* __restrict__ colwgt,
                                             const float* __restrict__ nself,
                                             const void* __restrict__ bias, int bFid,
                                             const float* __restrict__ other,
                                             ushort_t* __restrict__ Out,
                                             int n, const int* __restrict__ flags) {
    int node = (blockIdx.x * blockDim.x + threadIdx.x) >> 6;
    if (node >= n) return;
    int lane = threadIdx.x & 63;
    int quad = lane >> 4;
    int l16 = lane & 15;

    float acc[8];
#pragma unroll
    for (int i = 0; i < 8; ++i) acc[i] = 0.0f;

    int beg = row_ptr[node], end = row_ptr[node + 1];
    for (int bs = beg; bs < end; bs += 64) {
        int rem = end - bs;
        int nb = (rem < 64) ? rem : 64;
        int c = 0; float w = 0.0f;
        if (lane < nb) {
            uint2 m = colwgt[bs + lane];
            c = (int)m.x;
            w = __uint_as_float(m.y);
        }
        for (int j = 0; j < nb; j += 8) {
            int   s0 = __shfl(c, j + quad, 64);
            float w0 = __shfl(w, j + quad, 64);
            int   s1 = __shfl(c, j + 4 + quad, 64);
            float w1 = __shfl(w, j + 4 + quad, 64);
            uint4 v0 = *(const uint4*)(H + (size_t)s0 * 128 + l16 * 8);
            uint4 v1 = *(const uint4*)(H + (size_t)s1 * 128 + l16 * 8);
            acc[0] = fmaf(bf2f(v0.x & 0xffffu), w0, acc[0]);
            acc[1] = fmaf(bf2f(v0.x >> 16),     w0, acc[1]);
            acc[2] = fmaf(bf2f(v0.y & 0xffffu), w0, acc[2]);
            acc[3] = fmaf(bf2f(v0.y >> 16),     w0, acc[3]);
            acc[4] = fmaf(bf2f(v0.z & 0xffffu), w0, acc[4]);
            acc[5] = fmaf(bf2f(v0.z >> 16),     w0, acc[5]);
            acc[6] = fmaf(bf2f(v0.w & 0xffffu), w0, acc[6]);
            acc[7] = fmaf(bf2f(v0.w >> 16),     w0, acc[7]);
            acc[0] = fmaf(bf2f(v1.x & 0xffffu), w1, acc[0]);
            acc[1] = fmaf(bf2f(v1.x >> 16),     w1, acc[1]);
            acc[2] = fmaf(bf2f(v1.y & 0xffffu), w1, acc[2]);
            acc[3] = fmaf(bf2f(v1.y >> 16),     w1, acc[3]);
            acc[4] = fmaf(bf2f(v1.z & 0xffffu), w1, acc[4]);
            acc[5] = fmaf(bf2f(v1.z >> 16),     w1, acc[5]);
            acc[6] = fmaf(bf2f(v1.w & 0xffffu), w1, acc[6]);
            acc[7] = fmaf(bf2f(v1.w >> 16),     w1, acc[7]);
        }
    }

    // reduce the 4 quad-partials (lanes l16, l16+16, l16+32, l16+48)
#pragma unroll
    for (int i = 0; i < 8; ++i) {
        acc[i] += __shfl_xor(acc[i], 16, 64);
        acc[i] += __shfl_xor(acc[i], 32, 64);
    }

    if (quad == 0) {
        size_t nidx = (size_t)node * 128 + l16 * 8;
        float ns = nself[node];
        uint4 hv = *(const uint4*)(H + nidx);
        acc[0] += bf2f(hv.x & 0xffffu) * ns;
        acc[1] += bf2f(hv.x >> 16)     * ns;
        acc[2] += bf2f(hv.y & 0xffffu) * ns;
        acc[3] += bf2f(hv.y >> 16)     * ns;
        acc[4] += bf2f(hv.z & 0xffffu) * ns;
        acc[5] += bf2f(hv.z >> 16)     * ns;
        acc[6] += bf2f(hv.w & 0xffffu) * ns;
        acc[7] += bf2f(hv.w >> 16)     * ns;

        int bfm = flags[bFid];
#pragma unroll
        for (int i = 0; i < 8; ++i) acc[i] += loadF(bias, l16 * 8 + i, bfm);
        if (other) {
            const f32x4* op = (const f32x4*)(other + nidx);
            f32x4 o0 = op[0], o1 = op[1];
#pragma unroll
            for (int i = 0; i < 4; ++i) { acc[i] += o0[i]; acc[i + 4] += o1[i]; }
        }
#pragma unroll
        for (int i = 0; i < 8; ++i) acc[i] = fmaxf(acc[i], 0.0f);

        uint4 o;
        o.x = (uint_t)f2bf(acc[0]) | ((uint_t)f2bf(acc[1]) << 16);
        o.y = (uint_t)f2bf(acc[2]) | ((uint_t)f2bf(acc[3]) << 16);
        o.z = (uint_t)f2bf(acc[4]) | ((uint_t)f2bf(acc[5]) << 16);
        o.w = (uint_t)f2bf(acc[6]) | ((uint_t)f2bf(acc[7]) << 16);
        *(uint4*)(Out + nidx) = o;
    }
}

// ---------------- launch ----------------

extern "C" void kernel_launch(void* const* d_in, const int* in_sizes, int n_in,
                              void* d_out, int out_size, void* d_ws, size_t ws_size,
                              hipStream_t stream) {
    const int N = in_sizes[0] / 128;
    const int E = in_sizes[1] / 2;

    const void* x  = d_in[0];
    const int*  ei = (const int*)d_in[1];

    char* ws = (char*)d_ws;
    size_t used = 0;
    auto alloc = [&](size_t bytes) {
        char* p = ws + used;
        used += (bytes + 255) & ~(size_t)255;
        return p;
    };

    int*   flags   = (int*)alloc(64 * 4);
    int*   deg     = (int*)alloc((size_t)N * 4);
    int*   cnt     = (int*)alloc((size_t)N * 4);
    int*   row_ptr = (int*)alloc((size_t)(N + 1) * 4);
    float* dinv    = (float*)alloc((size_t)N * 4);
    float* nself   = (float*)alloc((size_t)N * 4);
    uint2* colwgt  = (uint2*)alloc((size_t)E * 8);
    int*   bsum    = (int*)alloc(256 * 4);
    ushort_t* Tcat = (ushort_t*)alloc(256 * 128 * 2);   // [W1^T ; Wres^T]
    ushort_t* T2   = (ushort_t*)alloc(128 * 128 * 2);
    ushort_t* T3   = (ushort_t*)alloc(128 * 128 * 2);
    ushort_t* Tlin = (ushort_t*)alloc(128 * 64 * 2);

    ushort_t* Hbuf = (ushort_t*)alloc((size_t)N * 128 * 2);  // gather source, bf16
    ushort_t* Act1 = (ushort_t*)alloc((size_t)N * 128 * 2);  // activations, bf16
    ushort_t* Act2 = (ushort_t*)alloc((size_t)N * 128 * 2);
    float*    Xres = (float*)alloc((size_t)N * 128 * 4);     // residual, fp32

    if (used > ws_size) return;

    DetectArgs da;
    for (int i = 0; i < 11; ++i) { da.t[i] = d_in[i == 0 ? 0 : i + 1]; da.elems[i] = in_sizes[i == 0 ? 0 : i + 1]; }
    da.ei = ei;
    da.flags = flags;

    const int B = 256;
    int gZero = (N + B - 1) / B;
    int gE    = (E + B - 1) / B;
    int gPack = (4 * 128 * 128 + 128 * 64 + B - 1) / B;
    int gGemm = (N + 63) / 64;
    int gAgg  = (N + 3) / 4;
    int nb    = (N + 1023) / 1024;

    k_detect<<<1, 64, 0, stream>>>(da);
    k_zero<<<gZero, B, 0, stream>>>(deg, N);
    k_pack<<<gPack, B, 0, stream>>>(d_in[2], d_in[4], d_in[6], d_in[8], d_in[10], flags,
                                    Tcat, T2, T3, Tlin);
    k_deg<<<gE, B, 0, stream>>>(ei, E, N, flags, deg);
    k_bsum<<<nb, B, 0, stream>>>(deg, N, bsum);
    k_bscan<<<1, B, 0, stream>>>(bsum, nb);
    k_rowptr<<<nb, B, 0, stream>>>(deg, bsum, N, row_ptr, cnt, dinv, nself);
    k_fill<<<gE, B, 0, stream>>>(ei, E, N, flags, cnt, dinv, colwgt);

    // layer 1 (fused dual GEMM): H = x@W1 (bf16), Xres = x@Wres + bres (fp32)
    k_gemm_l1<<<gGemm, B, 0, stream>>>(x, Tcat, d_in[9], Hbuf, Xres, N, flags);
    k_agg<<<gAgg, B, 0, stream>>>(Hbuf, row_ptr, colwgt, nself, d_in[3], 2,
                                  Xres, Act1, N, flags);

    // layer 2: H = Act1@W2 ; Act2 = relu(agg + b2)
    k_gemm<8><<<gGemm, B, 0, stream>>>(Act1, -1, 1, T2, nullptr, -1, Hbuf, 1, N, flags);
    k_agg<<<gAgg, B, 0, stream>>>(Hbuf, row_ptr, colwgt, nself, d_in[5], 4,
                                  nullptr, Act2, N, flags);

    // layer 3: H = Act2@W3 ; Act1 = relu(agg + b3)   (reuse Act1)
    k_gemm<8><<<gGemm, B, 0, stream>>>(Act2, -1, 1, T3, nullptr, -1, Hbuf, 1, N, flags);
    k_agg<<<gAgg, B, 0, stream>>>(Hbuf, row_ptr, colwgt, nself, d_in[7], 6,
                                  nullptr, Act1, N, flags);

    // final: out = Act1@Wlin + blin (fp32 out)
    k_gemm<4><<<gGemm, B, 0, stream>>>(Act1, -1, 1, Tlin, d_in[11], 10,
                                       d_out, 0, N, flags);
}

// Round 9
// 348.146 us; speedup vs baseline: 1.1314x; 1.1314x over previous
//
#include <hip/hip_runtime.h>

typedef unsigned short ushort_t;
typedef unsigned int uint_t;

typedef __bf16 bf16x8 __attribute__((ext_vector_type(8)));
typedef float f32x4 __attribute__((ext_vector_type(4)));

union BFU { ushort_t u; __bf16 h; };

__device__ __forceinline__ float bf2f(uint_t u) {
    union { uint_t i; float f; } v; v.i = u << 16; return v.f;
}
__device__ __forceinline__ ushort_t f2bf(float f) {
    union { float f; uint_t i; } v; v.f = f;
    uint_t r = v.i + 0x7fffu + ((v.i >> 16) & 1u);
    return (ushort_t)(r >> 16);
}
// mode: 1 = bf16 storage, 0 = fp32 storage
__device__ __forceinline__ float loadF(const void* p, size_t i, int isBf16) {
    return isBf16 ? bf2f((uint_t)((const ushort_t*)p)[i]) : ((const float*)p)[i];
}

// ---------------- dtype detection ----------------
// flags[0..10]: x,W1,b1,W2,b2,W3,b3,Wres,bres,Wlin,blin  (1=bf16, 0=fp32)
// flags[11]: edge_index is int64 (1) or int32 (0)
struct DetectArgs {
    const void* t[11];
    int elems[11];
    const int* ei;
    int* flags;
};

__global__ void k_detect(DetectArgs a) {
    int t = threadIdx.x;
    if (t < 11) {
        const uint_t* w = (const uint_t*)a.t[t];
        int n = a.elems[t] / 2; if (n > 64) n = 64;
        int cnt = 0;
        for (int i = 0; i < n; ++i) {
            uint_t field = (w[i] >> 7) & 0xFFu;
            cnt += (field >= 100u && field <= 135u);
        }
        a.flags[t] = (cnt * 10 >= n * 6) ? 1 : 0;
    } else if (t == 11) {
        int nz = 0;
        for (int i = 0; i < 64; ++i) nz += (a.ei[2 * i + 1] != 0);
        a.flags[11] = (nz == 0) ? 1 : 0;
    }
}

// ---------------- preprocessing ----------------

__global__ void k_zero(int* p, int n) {
    int i = blockIdx.x * blockDim.x + threadIdx.x;
    if (i < n) p[i] = 0;
}

__global__ void k_deg(const int* __restrict__ ei, int E, int N,
                      const int* __restrict__ flags, int* __restrict__ deg) {
    int e = blockIdx.x * blockDim.x + threadIdx.x;
    if (e < E) {
        int is64 = flags[11];
        int d = is64 ? ei[2 * E + 2 * e] : ei[E + e];
        if ((unsigned)d < (unsigned)N) atomicAdd(&deg[d], 1);
    }
}

// ---- 3-phase parallel exclusive scan of deg -> row_ptr (+ dinv/nself/cnt) ----

__global__ __launch_bounds__(256) void k_bsum(const int* __restrict__ deg, int n,
                                              int* __restrict__ bsum) {
    int base = blockIdx.x * 1024;
    int local = 0;
#pragma unroll
    for (int j = 0; j < 4; ++j) {
        int idx = base + threadIdx.x + j * 256;
        if (idx < n) local += deg[idx];
    }
    __shared__ int s[4];
#pragma unroll
    for (int off = 32; off; off >>= 1) local += __shfl_down(local, off, 64);
    if ((threadIdx.x & 63) == 0) s[threadIdx.x >> 6] = local;
    __syncthreads();
    if (threadIdx.x == 0) bsum[blockIdx.x] = s[0] + s[1] + s[2] + s[3];
}

__global__ __launch_bounds__(256) void k_bscan(int* __restrict__ bsum, int nb) {
    __shared__ int s[256];
    int t = threadIdx.x;
    int v = (t < nb) ? bsum[t] : 0;
    s[t] = v;
    __syncthreads();
    for (int off = 1; off < 256; off <<= 1) {
        int u = (t >= off) ? s[t - off] : 0;
        __syncthreads();
        s[t] += u;
        __syncthreads();
    }
    if (t < nb) bsum[t] = s[t] - v;   // exclusive
}

// writes row_ptr, dinv, nself AND pre-seeds cnt = row_ptr (fill's atomic counter)
__global__ __launch_bounds__(256) void k_rowptr(const int* __restrict__ deg,
                                                const int* __restrict__ boff, int n,
                                                int* __restrict__ row_ptr,
                                                int* __restrict__ cnt,
                                                float* __restrict__ dinv,
                                                float* __restrict__ nself) {
    __shared__ int s[256];
    int t = threadIdx.x;
    int base = blockIdx.x * 1024 + t * 4;
    int v0 = (base + 0 < n) ? deg[base + 0] : 0;
    int v1 = (base + 1 < n) ? deg[base + 1] : 0;
    int v2 = (base + 2 < n) ? deg[base + 2] : 0;
    int v3 = (base + 3 < n) ? deg[base + 3] : 0;
    int tot = v0 + v1 + v2 + v3;
    s[t] = tot;
    __syncthreads();
    for (int off = 1; off < 256; off <<= 1) {
        int u = (t >= off) ? s[t - off] : 0;
        __syncthreads();
        s[t] += u;
        __syncthreads();
    }
    int run = boff[blockIdx.x] + ((t == 0) ? 0 : s[t - 1]);
    int vals[4] = {v0, v1, v2, v3};
#pragma unroll
    for (int j = 0; j < 4; ++j) {
        int idx = base + j;
        if (idx < n) {
            row_ptr[idx] = run;
            cnt[idx] = run;
            run += vals[j];
            float df = (float)vals[j] + 1.0f;
            dinv[idx] = rsqrtf(df);
            nself[idx] = 1.0f / df;
        }
    }
    if (blockIdx.x == gridDim.x - 1 && t == 255) row_ptr[n] = boff[blockIdx.x] + s[255];
}

// fill CSR: single packed 8B store per edge {col, wgt bits}; cnt pre-seeded to row_ptr
__global__ void k_fill(const int* __restrict__ ei, int E, int N,
                       const int* __restrict__ flags,
                       int* __restrict__ cnt,
                       const float* __restrict__ dinv,
                       uint2* __restrict__ colwgt) {
    int e = blockIdx.x * blockDim.x + threadIdx.x;
    if (e < E) {
        int is64 = flags[11];
        int s = is64 ? ei[2 * e] : ei[e];
        int d = is64 ? ei[2 * E + 2 * e] : ei[E + e];
        if ((unsigned)d < (unsigned)N) {
            int pos = atomicAdd(&cnt[d], 1);
            int ss = ((unsigned)s < (unsigned)N) ? s : 0;
            float w = dinv[ss] * dinv[d];
            uint2 pk;
            pk.x = (uint_t)ss;
            pk.y = __float_as_uint(w);
            colwgt[pos] = pk;
        }
    }
}

// transpose + canonicalize weights to bf16.
// Tcat[256 x 128] = [W1^T ; Wres^T]; T2,T3,Tlin as before.
__global__ void k_pack(const void* __restrict__ W1, const void* __restrict__ W2,
                       const void* __restrict__ W3, const void* __restrict__ Wr,
                       const void* __restrict__ Wl, const int* __restrict__ flags,
                       ushort_t* __restrict__ Tcat, ushort_t* __restrict__ T2,
                       ushort_t* __restrict__ T3, ushort_t* __restrict__ Tl) {
    int i = blockIdx.x * blockDim.x + threadIdx.x;
    const int SQ = 128 * 128;
    if (i < 4 * SQ) {
        int m = i / SQ, r = i % SQ;
        int k = r / 128, f = r % 128;
        const void* W = (m == 0) ? W1 : (m == 1) ? W2 : (m == 2) ? W3 : Wr;
        int fid = (m == 0) ? 1 : (m == 1) ? 3 : (m == 2) ? 5 : 7;
        ushort_t* T = (m == 0) ? Tcat : (m == 1) ? T2 : (m == 2) ? T3 : (Tcat + SQ);
        T[f * 128 + k] = f2bf(loadF(W, (size_t)k * 128 + f, flags[fid]));
    } else if (i < 4 * SQ + 128 * 64) {
        int r = i - 4 * SQ;
        int k = r / 64, f = r % 64;
        Tl[f * 128 + k] = f2bf(loadF(Wl, (size_t)k * 64 + f, flags[9]));
    }
}

// ===== LDS-staged GEMM =====
// WT staged into LDS in swizzled fragment layout: uint4 index
// ((kk*NCT + c)*64 + quad*16 + l16)  <- lane-contiguous per (kk,c) -> conflict-free b128.
// Each wave computes 2 row-tiles (32 rows); block = 4 waves = 128 rows.
// All A-fragments preloaded before the K-loop (max MLP); B from LDS.

template <int NCT>
__device__ __forceinline__ void stage_B(const ushort_t* __restrict__ WT, uint4* lds) {
    int t = threadIdx.x;
#pragma unroll
    for (int i = 0; i < NCT; ++i) {
        int g = i * 256 + t;
        uint4 v = ((const uint4*)WT)[g];
        int col = g >> 4, k8 = g & 15;
        int c = col >> 4, l16c = col & 15;
        int kk = k8 >> 2, q = k8 & 3;
        lds[((kk * NCT + c) << 6) + (q << 4) + l16c] = v;
    }
    __syncthreads();
}

__device__ __forceinline__ void load_A2(const void* __restrict__ A, int a16,
                                        int ar0, int ar1, int quad,
                                        bf16x8 afrag[2][4]) {
    if (a16) {
        const ushort_t* p0 = (const ushort_t*)A + (size_t)ar0 * 128 + quad * 8;
        const ushort_t* p1 = (const ushort_t*)A + (size_t)ar1 * 128 + quad * 8;
#pragma unroll
        for (int kk = 0; kk < 4; ++kk) {
            afrag[0][kk] = *(const bf16x8*)(p0 + kk * 32);
            afrag[1][kk] = *(const bf16x8*)(p1 + kk * 32);
        }
    } else {
        const float* p0 = (const float*)A + (size_t)ar0 * 128 + quad * 8;
        const float* p1 = (const float*)A + (size_t)ar1 * 128 + quad * 8;
#pragma unroll
        for (int kk = 0; kk < 4; ++kk) {
            f32x4 u0 = *(const f32x4*)(p0 + kk * 32);
            f32x4 u1 = *(const f32x4*)(p0 + kk * 32 + 4);
            f32x4 v0 = *(const f32x4*)(p1 + kk * 32);
            f32x4 v1 = *(const f32x4*)(p1 + kk * 32 + 4);
#pragma unroll
            for (int j = 0; j < 4; ++j) {
                BFU e;
                e.u = f2bf(u0[j]); afrag[0][kk][j] = e.h;
                e.u = f2bf(u1[j]); afrag[0][kk][j + 4] = e.h;
                e.u = f2bf(v0[j]); afrag[1][kk][j] = e.h;
                e.u = f2bf(v1[j]); afrag[1][kk][j + 4] = e.h;
            }
        }
    }
}

// generic: C[M x NCT*16], optional bias
template <int NCT>
__global__ __launch_bounds__(256, 2) void k_gemm2(const void* __restrict__ A, int aFid, int aFix,
                                                  const ushort_t* __restrict__ WT,
                                                  const void* __restrict__ bias, int bFid,
                                                  void* __restrict__ C, int cFix,
                                                  int M, const int* __restrict__ flags) {
    __shared__ uint4 lds[NCT * 256];
    stage_B<NCT>(WT, lds);

    const int F = NCT * 16;
    int t = threadIdx.x;
    int wave = t >> 6, lane = t & 63;
    int quad = lane >> 4, l16 = lane & 15;
    int rowBase = blockIdx.x * 128 + wave * 32;

    int a16 = (aFid >= 0) ? flags[aFid] : aFix;
    int ar0 = rowBase + l16;      if (ar0 >= M) ar0 = M - 1;
    int ar1 = rowBase + 16 + l16; if (ar1 >= M) ar1 = M - 1;

    bf16x8 afrag[2][4];
    load_A2(A, a16, ar0, ar1, quad, afrag);

    f32x4 acc[2][NCT];
#pragma unroll
    for (int r = 0; r < 2; ++r)
#pragma unroll
        for (int c = 0; c < NCT; ++c) acc[r][c] = (f32x4){0.f, 0.f, 0.f, 0.f};

#pragma unroll
    for (int kk = 0; kk < 4; ++kk) {
#pragma unroll
        for (int c = 0; c < NCT; ++c) {
            bf16x8 b = *(const bf16x8*)&lds[((kk * NCT + c) << 6) + lane];
            acc[0][c] = __builtin_amdgcn_mfma_f32_16x16x32_bf16(afrag[0][kk], b, acc[0][c], 0, 0, 0);
            acc[1][c] = __builtin_amdgcn_mfma_f32_16x16x32_bf16(afrag[1][kk], b, acc[1][c], 0, 0, 0);
        }
    }

    int bf = (bias && bFid >= 0) ? flags[bFid] : 1;
#pragma unroll
    for (int r = 0; r < 2; ++r) {
#pragma unroll
        for (int c = 0; c < NCT; ++c) {
            int colg = c * 16 + l16;
            float bv = bias ? loadF(bias, colg, bf) : 0.0f;
#pragma unroll
            for (int q = 0; q < 4; ++q) {
                int row = rowBase + r * 16 + quad * 4 + q;
                if (row < M) {
                    float v = acc[r][c][q] + bv;
                    if (cFix) ((ushort_t*)C)[(size_t)row * F + colg] = f2bf(v);
                    else      ((float*)C)[(size_t)row * F + colg] = v;
                }
            }
        }
    }
}

// layer-1 dual output: col-tiles 0..7 -> Hout (bf16), 8..15 -> Xres + bres (fp32)
__global__ __launch_bounds__(256, 1) void k_gemm_l1(const void* __restrict__ A,
                                                    const ushort_t* __restrict__ Tcat,
                                                    const void* __restrict__ bres,
                                                    ushort_t* __restrict__ Hout,
                                                    float* __restrict__ Xres,
                                                    int M, const int* __restrict__ flags) {
    __shared__ uint4 lds[16 * 256];
    stage_B<16>(Tcat, lds);

    int t = threadIdx.x;
    int wave = t >> 6, lane = t & 63;
    int quad = lane >> 4, l16 = lane & 15;
    int rowBase = blockIdx.x * 128 + wave * 32;

    int a16 = flags[0];
    int ar0 = rowBase + l16;      if (ar0 >= M) ar0 = M - 1;
    int ar1 = rowBase + 16 + l16; if (ar1 >= M) ar1 = M - 1;

    bf16x8 afrag[2][4];
    load_A2(A, a16, ar0, ar1, quad, afrag);

    f32x4 acc[2][16];
#pragma unroll
    for (int r = 0; r < 2; ++r)
#pragma unroll
        for (int c = 0; c < 16; ++c) acc[r][c] = (f32x4){0.f, 0.f, 0.f, 0.f};

#pragma unroll
    for (int kk = 0; kk < 4; ++kk) {
#pragma unroll
        for (int c = 0; c < 16; ++c) {
            bf16x8 b = *(const bf16x8*)&lds[((kk * 16 + c) << 6) + lane];
            acc[0][c] = __builtin_amdgcn_mfma_f32_16x16x32_bf16(afrag[0][kk], b, acc[0][c], 0, 0, 0);
            acc[1][c] = __builtin_amdgcn_mfma_f32_16x16x32_bf16(afrag[1][kk], b, acc[1][c], 0, 0, 0);
        }
    }

    int bf = flags[8];
#pragma unroll
    for (int r = 0; r < 2; ++r) {
#pragma unroll
        for (int c = 0; c < 16; ++c) {
            int colg = c * 16 + l16;
            float bv = (c >= 8) ? loadF(bres, colg - 128, bf) : 0.0f;
#pragma unroll
            for (int q = 0; q < 4; ++q) {
                int row = rowBase + r * 16 + quad * 4 + q;
                if (row < M) {
                    float v = acc[r][c][q] + bv;
                    if (c < 8) Hout[(size_t)row * 128 + colg] = f2bf(v);
                    else       Xres[(size_t)row * 128 + (colg - 128)] = v;
                }
            }
        }
    }
}

// ---------------- aggregation: one wave per node, batched-MLP gather (R7) ----------------
__global__ __launch_bounds__(256) void k_agg(const ushort_t* __restrict__ H,
                                             const int* __restrict__ row_ptr,
                                             const uint2* __restrict__ colwgt,
                                             const float* __restrict__ nself,
                                             const void* __restrict__ bias, int bFid,
                                             const float* __restrict__ other,
                                             ushort_t* __restrict__ Out,
                                             int n, const int* __restrict__ flags) {
    int node = (blockIdx.x * blockDim.x + threadIdx.x) >> 6;
    if (node >= n) return;
    int lane = threadIdx.x & 63;
    int f = lane * 2;

    float ns = nself[node];
    size_t nidx = (size_t)node * 128 + f;

    uint_t hv = *(const uint_t*)(H + nidx);
    float a0 = bf2f(hv & 0xffffu) * ns;
    float a1 = bf2f(hv >> 16) * ns;

    int beg = row_ptr[node], end = row_ptr[node + 1];
    for (int bs = beg; bs < end; bs += 64) {
        int rem = end - bs;
        int nb = (rem < 64) ? rem : 64;
        uint2 m = (lane < nb) ? colwgt[bs + lane] : (uint2){0u, 0u};
        int c = (int)m.x;
        float w = __uint_as_float(m.y);

        int j = 0;
        for (; j + 8 <= nb; j += 8) {
            int si[8]; float wi[8]; uint_t vi[8];
#pragma unroll
            for (int q = 0; q < 8; ++q) {
                si[q] = __shfl(c, j + q, 64);
                wi[q] = __shfl(w, j + q, 64);
            }
#pragma unroll
            for (int q = 0; q < 8; ++q)
                vi[q] = *(const uint_t*)(H + (size_t)si[q] * 128 + f);
#pragma unroll
            for (int q = 0; q < 8; ++q) {
                a0 = fmaf(bf2f(vi[q] & 0xffffu), wi[q], a0);
                a1 = fmaf(bf2f(vi[q] >> 16), wi[q], a1);
            }
        }
        for (; j + 4 <= nb; j += 4) {
            int si[4]; float wi[4]; uint_t vi[4];
#pragma unroll
            for (int q = 0; q < 4; ++q) {
                si[q] = __shfl(c, j + q, 64);
                wi[q] = __shfl(w, j + q, 64);
            }
#pragma unroll
            for (int q = 0; q < 4; ++q)
                vi[q] = *(const uint_t*)(H + (size_t)si[q] * 128 + f);
#pragma unroll
            for (int q = 0; q < 4; ++q) {
                a0 = fmaf(bf2f(vi[q] & 0xffffu), wi[q], a0);
                a1 = fmaf(bf2f(vi[q] >> 16), wi[q], a1);
            }
        }
        for (; j < nb; ++j) {
            int sj = __shfl(c, j, 64);
            float wj = __shfl(w, j, 64);
            uint_t v = *(const uint_t*)(H + (size_t)sj * 128 + f);
            a0 = fmaf(bf2f(v & 0xffffu), wj, a0);
            a1 = fmaf(bf2f(v >> 16), wj, a1);
        }
    }

    int bfm = flags[bFid];
    a0 += loadF(bias, f, bfm);
    a1 += loadF(bias, f + 1, bfm);
    if (other) {
        a0 += other[nidx];
        a1 += other[nidx + 1];
    }
    a0 = fmaxf(a0, 0.0f);
    a1 = fmaxf(a1, 0.0f);
    uint_t outv = (uint_t)f2bf(a0) | ((uint_t)f2bf(a1) << 16);
    *(uint_t*)(Out + nidx) = outv;
}

// ---------------- launch ----------------

extern "C" void kernel_launch(void* const* d_in, const int* in_sizes, int n_in,
                              void* d_out, int out_size, void* d_ws, size_t ws_size,
                              hipStream_t stream) {
    const int N = in_sizes[0] / 128;
    const int E = in_sizes[1] / 2;

    const void* x  = d_in[0];
    const int*  ei = (const int*)d_in[1];

    char* ws = (char*)d_ws;
    size_t used = 0;
    auto alloc = [&](size_t bytes) {
        char* p = ws + used;
        used += (bytes + 255) & ~(size_t)255;
        return p;
    };

    int*   flags   = (int*)alloc(64 * 4);
    int*   deg     = (int*)alloc((size_t)N * 4);
    int*   cnt     = (int*)alloc((size_t)N * 4);
    int*   row_ptr = (int*)alloc((size_t)(N + 1) * 4);
    float* dinv    = (float*)alloc((size_t)N * 4);
    float* nself   = (float*)alloc((size_t)N * 4);
    uint2* colwgt  = (uint2*)alloc((size_t)E * 8);
    int*   bsum    = (int*)alloc(256 * 4);
    ushort_t* Tcat = (ushort_t*)alloc(256 * 128 * 2);   // [W1^T ; Wres^T]
    ushort_t* T2   = (ushort_t*)alloc(128 * 128 * 2);
    ushort_t* T3   = (ushort_t*)alloc(128 * 128 * 2);
    ushort_t* Tlin = (ushort_t*)alloc(128 * 64 * 2);

    ushort_t* Hbuf = (ushort_t*)alloc((size_t)N * 128 * 2);  // gather source, bf16
    ushort_t* Act1 = (ushort_t*)alloc((size_t)N * 128 * 2);  // activations, bf16
    ushort_t* Act2 = (ushort_t*)alloc((size_t)N * 128 * 2);
    float*    Xres = (float*)alloc((size_t)N * 128 * 4);     // residual, fp32

    if (used > ws_size) return;

    DetectArgs da;
    for (int i = 0; i < 11; ++i) { da.t[i] = d_in[i == 0 ? 0 : i + 1]; da.elems[i] = in_sizes[i == 0 ? 0 : i + 1]; }
    da.ei = ei;
    da.flags = flags;

    const int B = 256;
    int gZero = (N + B - 1) / B;
    int gE    = (E + B - 1) / B;
    int gPack = (4 * 128 * 128 + 128 * 64 + B - 1) / B;
    int gGemm = (N + 127) / 128;
    int gAgg  = (N + 3) / 4;
    int nb    = (N + 1023) / 1024;

    k_detect<<<1, 64, 0, stream>>>(da);
    k_zero<<<gZero, B, 0, stream>>>(deg, N);
    k_pack<<<gPack, B, 0, stream>>>(d_in[2], d_in[4], d_in[6], d_in[8], d_in[10], flags,
                                    Tcat, T2, T3, Tlin);
    k_deg<<<gE, B, 0, stream>>>(ei, E, N, flags, deg);
    k_bsum<<<nb, B, 0, stream>>>(deg, N, bsum);
    k_bscan<<<1, B, 0, stream>>>(bsum, nb);
    k_rowptr<<<nb, B, 0, stream>>>(deg, bsum, N, row_ptr, cnt, dinv, nself);
    k_fill<<<gE, B, 0, stream>>>(ei, E, N, flags, cnt, dinv, colwgt);

    // layer 1 (fused dual GEMM): H = x@W1 (bf16), Xres = x@Wres + bres (fp32)
    k_gemm_l1<<<gGemm, B, 0, stream>>>(x, Tcat, d_in[9], Hbuf, Xres, N, flags);
    k_agg<<<gAgg, B, 0, stream>>>(Hbuf, row_ptr, colwgt, nself, d_in[3], 2,
                                  Xres, Act1, N, flags);

    // layer 2: H = Act1@W2 ; Act2 = relu(agg + b2)
    k_gemm2<8><<<gGemm, B, 0, stream>>>(Act1, -1, 1, T2, nullptr, -1, Hbuf, 1, N, flags);
    k_agg<<<gAgg, B, 0, stream>>>(Hbuf, row_ptr, colwgt, nself, d_in[5], 4,
                                  nullptr, Act2, N, flags);

    // layer 3: H = Act2@W3 ; Act1 = relu(agg + b3)   (reuse Act1)
    k_gemm2<8><<<gGemm, B, 0, stream>>>(Act2, -1, 1, T3, nullptr, -1, Hbuf, 1, N, flags);
    k_agg<<<gAgg, B, 0, stream>>>(Hbuf, row_ptr, colwgt, nself, d_in[7], 6,
                                  nullptr, Act1, N, flags);

    // final: out = Act1@Wlin + blin (fp32 out)
    k_gemm2<4><<<gGemm, B, 0, stream>>>(Act1, -1, 1, Tlin, d_in[11], 10,
                                        d_out, 0, N, flags);
}